// Round 1
// baseline (2116.841 us; speedup 1.0000x reference)
//
#include <hip/hip_runtime.h>

#define NQ 16384
#define NK 16384
#define DD 256
#define DVV 256
#define BM 64
#define BN 64
#define NCHUNK (NK / BN)            // 256
#define X_ELEMS ((size_t)NQ * DVV)  // 4194304

// LDS strides (in halfs / floats), chosen so row byte-stride ≡ 8 (mod 16):
// 8B-aligned ds ops, ~2-way max bank aliasing (free).
#define KST 260   // K chunk rows [64][260] halfs
#define VST 68    // Vt chunk rows [256][68] halfs
#define PST 68    // P tile [64][68] halfs
#define SST 68    // S tile [64][68] floats (272B rows -> 16B aligned, b128 OK)

typedef _Float16 h4 __attribute__((ext_vector_type(4)));
typedef _Float16 h8 __attribute__((ext_vector_type(8)));
typedef float f32x16 __attribute__((ext_vector_type(16)));
typedef float f32x4 __attribute__((ext_vector_type(4)));

__device__ __forceinline__ h8 ldh8(const _Float16* p) {
  h4 x = *(const h4*)p;
  h4 y = *(const h4*)(p + 4);
  return __builtin_shufflevector(x, y, 0, 1, 2, 3, 4, 5, 6, 7);
}

// fp32 -> fp16 elementwise (K)
__global__ void convert_k(const float* __restrict__ src, _Float16* __restrict__ dst) {
  size_t idx = ((size_t)blockIdx.x * blockDim.x + threadIdx.x) * 8;
  float4 a = *(const float4*)(src + idx);
  float4 b = *(const float4*)(src + idx + 4);
  h8 h;
  h[0] = (_Float16)a.x; h[1] = (_Float16)a.y; h[2] = (_Float16)a.z; h[3] = (_Float16)a.w;
  h[4] = (_Float16)b.x; h[5] = (_Float16)b.y; h[6] = (_Float16)b.z; h[7] = (_Float16)b.w;
  *(h8*)(dst + idx) = h;
}

// V[NK][DVV] fp32 -> Vt[DVV][NK] fp16 (so PV B-operand reads are k-contiguous)
__global__ void transpose_v(const float* __restrict__ V, _Float16* __restrict__ Vt) {
  __shared__ _Float16 tile[64][72];
  const int t = threadIdx.x;
  const int k0 = blockIdx.x * 64;
  const int v0 = blockIdx.y * 64;
  const int r = t >> 2, s = t & 3;
  const float4* src = (const float4*)(V + (size_t)(k0 + r) * DVV + v0 + s * 16);
  float4 a0 = src[0], a1 = src[1], a2 = src[2], a3 = src[3];
  _Float16* dp = &tile[r][s * 16];
  dp[0] = (_Float16)a0.x;  dp[1] = (_Float16)a0.y;  dp[2] = (_Float16)a0.z;  dp[3] = (_Float16)a0.w;
  dp[4] = (_Float16)a1.x;  dp[5] = (_Float16)a1.y;  dp[6] = (_Float16)a1.z;  dp[7] = (_Float16)a1.w;
  dp[8] = (_Float16)a2.x;  dp[9] = (_Float16)a2.y;  dp[10] = (_Float16)a2.z; dp[11] = (_Float16)a2.w;
  dp[12] = (_Float16)a3.x; dp[13] = (_Float16)a3.y; dp[14] = (_Float16)a3.z; dp[15] = (_Float16)a3.w;
  __syncthreads();
  union { _Float16 h[16]; uint4 u[2]; } ob;
#pragma unroll
  for (int j = 0; j < 16; ++j) ob.h[j] = tile[s * 16 + j][r];
  uint4* dst = (uint4*)(Vt + (size_t)(v0 + r) * NK + k0 + s * 16);
  dst[0] = ob.u[0];
  dst[1] = ob.u[1];
}

__device__ __forceinline__ void stage_k(const _Float16* __restrict__ Kh,
                                        _Float16* KV, int ck, int t) {
  const uint4* src = (const uint4*)(Kh + (size_t)ck * (BN * DD));
#pragma unroll
  for (int i = 0; i < 8; ++i) {
    int idx = i * 256 + t;            // 0..2047 16B units, chunk is contiguous
    int r = idx >> 5, c = idx & 31;
    uint4 v = src[idx];
    uint2* d = (uint2*)&KV[r * KST + c * 8];
    d[0] = make_uint2(v.x, v.y);
    d[1] = make_uint2(v.z, v.w);
  }
}

// S = Q K^T for this block's 64 rows x 64 cols; result scattered to Sb[64][SST]
__device__ __forceinline__ void compute_s(const h8* qf, const _Float16* KV, float* Sb,
                                          int wm, int ncol, int dhi, int hi) {
  f32x16 acc;
#pragma unroll
  for (int i = 0; i < 16; ++i) acc[i] = 0.0f;
#pragma unroll
  for (int ks = 0; ks < 16; ++ks) {
    const _Float16* bp = &KV[ncol * KST + ks * 16 + dhi];
    h8 b = ldh8(bp);
    acc = __builtin_amdgcn_mfma_f32_32x32x16_f16(qf[ks], b, acc, 0, 0, 0);
  }
#pragma unroll
  for (int r = 0; r < 16; ++r) {
    int row = wm * 32 + (r & 3) + 8 * (r >> 2) + 4 * hi;
    Sb[row * SST + ncol] = acc[r];
  }
}

__global__ __launch_bounds__(256, 1)
void attn_main(const float* __restrict__ Qg,
               const _Float16* __restrict__ Kh,
               const _Float16* __restrict__ Vtg,
               float* __restrict__ outg) {
  // union staging buffer: K chunk [64][KST] (16640 halfs) / Vt chunk [256][VST] (17408 halfs)
  __shared__ __align__(16) _Float16 KV[17408];
  __shared__ __align__(16) float Sb[BM * SST];
  __shared__ __align__(16) _Float16 Pb[BM * PST];
  __shared__ float m_s[BM], l_s[BM], rl_s[BM];

  const int t = threadIdx.x;
  const int lane = t & 63;
  const int w = t >> 6;        // wave id 0..3
  const int l31 = lane & 31;
  const int hi = lane >> 5;    // 0/1
  const int dhi = hi * 8;
  const int q0 = blockIdx.x * BM;
  const int wm = w >> 1;       // S-phase row half
  const int wn = w & 1;        // S-phase col half
  const int ncol = wn * 32 + l31;
  const int srow = t >> 2;     // softmax: 4 threads per row
  const int sseg = t & 3;

  // ---- cache Q fragments in registers (64 VGPRs), fp32->fp16 on the fly ----
  h8 qf[16];
  {
    const float* qp = Qg + (size_t)(q0 + wm * 32 + l31) * DD + dhi;
#pragma unroll
    for (int ks = 0; ks < 16; ++ks) {
      float4 a = *(const float4*)(qp + ks * 16);
      float4 b = *(const float4*)(qp + ks * 16 + 4);
      h8 f;
      f[0] = (_Float16)a.x; f[1] = (_Float16)a.y; f[2] = (_Float16)a.z; f[3] = (_Float16)a.w;
      f[4] = (_Float16)b.x; f[5] = (_Float16)b.y; f[6] = (_Float16)b.z; f[7] = (_Float16)b.w;
      qf[ks] = f;
    }
  }

  if (t < BM) { m_s[t] = -1e30f; l_s[t] = 0.0f; }

  // ================= phase 1: exact row max + sum (online) =================
  for (int ck = 0; ck < NCHUNK; ++ck) {
    __syncthreads();
    stage_k(Kh, KV, ck, t);
    __syncthreads();
    compute_s(qf, KV, Sb, wm, ncol, dhi, hi);
    __syncthreads();
    {
      const f32x4* sp = (const f32x4*)&Sb[srow * SST + sseg * 16];
      f32x4 sv0 = sp[0], sv1 = sp[1], sv2 = sp[2], sv3 = sp[3];
      float mx = sv0[0];
#pragma unroll
      for (int j = 1; j < 4; ++j) mx = fmaxf(mx, sv0[j]);
#pragma unroll
      for (int j = 0; j < 4; ++j) mx = fmaxf(mx, sv1[j]);
#pragma unroll
      for (int j = 0; j < 4; ++j) mx = fmaxf(mx, sv2[j]);
#pragma unroll
      for (int j = 0; j < 4; ++j) mx = fmaxf(mx, sv3[j]);
      mx = fmaxf(mx, __shfl_xor(mx, 1));
      mx = fmaxf(mx, __shfl_xor(mx, 2));
      float mold = m_s[srow];
      float mnew = fmaxf(mold, mx);
      float sum = 0.0f;
#pragma unroll
      for (int j = 0; j < 4; ++j) sum += __expf(sv0[j] - mnew);
#pragma unroll
      for (int j = 0; j < 4; ++j) sum += __expf(sv1[j] - mnew);
#pragma unroll
      for (int j = 0; j < 4; ++j) sum += __expf(sv2[j] - mnew);
#pragma unroll
      for (int j = 0; j < 4; ++j) sum += __expf(sv3[j] - mnew);
      sum += __shfl_xor(sum, 1);
      sum += __shfl_xor(sum, 2);
      if (sseg == 0) {
        l_s[srow] = l_s[srow] * __expf(mold - mnew) + sum;
        m_s[srow] = mnew;
      }
    }
  }
  __syncthreads();
  if (t < BM) rl_s[t] = 1.0f / l_s[t];

  // ================= phase 2: P write + PV accumulate =================
  f32x16 oacc[2][2];
#pragma unroll
  for (int a = 0; a < 2; ++a)
#pragma unroll
    for (int b = 0; b < 2; ++b)
#pragma unroll
      for (int i = 0; i < 16; ++i) oacc[a][b][i] = 0.0f;

  float* Pg = outg + X_ELEMS;

  for (int ck = 0; ck < NCHUNK; ++ck) {
    __syncthreads();
    stage_k(Kh, KV, ck, t);
    __syncthreads();
    compute_s(qf, KV, Sb, wm, ncol, dhi, hi);
    __syncthreads();
    // --- stage Vt chunk into KV (overwrites K) + softmax from Sb (disjoint) ---
    {
#pragma unroll
      for (int i = 0; i < 8; ++i) {
        int idx = i * 256 + t;          // 0..2047, 16B units
        int v = idx >> 3, seg = idx & 7;
        uint4 val = *(const uint4*)(Vtg + (size_t)v * NK + (size_t)ck * BN + seg * 8);
        uint2* d = (uint2*)&KV[v * VST + seg * 8];
        d[0] = make_uint2(val.x, val.y);
        d[1] = make_uint2(val.z, val.w);
      }
      const f32x4* sp = (const f32x4*)&Sb[srow * SST + sseg * 16];
      f32x4 sv[4] = {sp[0], sp[1], sp[2], sp[3]};
      float m = m_s[srow];
      float rl = rl_s[srow];
      float* gp = Pg + (size_t)(q0 + srow) * NK + (size_t)ck * BN + sseg * 16;
      _Float16* pb = &Pb[srow * PST + sseg * 16];
#pragma unroll
      for (int g = 0; g < 4; ++g) {
        f32x4 p;
#pragma unroll
        for (int j = 0; j < 4; ++j) p[j] = __expf(sv[g][j] - m) * rl;
        *(f32x4*)(gp + g * 4) = p;      // coalesced 64B/thread, 256B per row-quad
        h4 hp;
#pragma unroll
        for (int j = 0; j < 4; ++j) hp[j] = (_Float16)p[j];
        *(h4*)(pb + g * 4) = hp;
      }
    }
    __syncthreads();
    // --- PV: O[q][v] += P[q][n] * V[n][v]; A from Pb, B from Vt(KV) ---
#pragma unroll
    for (int ks = 0; ks < 4; ++ks) {
      int kk = ks * 16 + dhi;
      h8 a0 = ldh8(&Pb[l31 * PST + kk]);
      h8 a1 = ldh8(&Pb[(32 + l31) * PST + kk]);
      h8 b0 = ldh8(&KV[(w * 64 + l31) * VST + kk]);
      h8 b1 = ldh8(&KV[(w * 64 + 32 + l31) * VST + kk]);
      oacc[0][0] = __builtin_amdgcn_mfma_f32_32x32x16_f16(a0, b0, oacc[0][0], 0, 0, 0);
      oacc[0][1] = __builtin_amdgcn_mfma_f32_32x32x16_f16(a0, b1, oacc[0][1], 0, 0, 0);
      oacc[1][0] = __builtin_amdgcn_mfma_f32_32x32x16_f16(a1, b0, oacc[1][0], 0, 0, 0);
      oacc[1][1] = __builtin_amdgcn_mfma_f32_32x32x16_f16(a1, b1, oacc[1][1], 0, 0, 0);
    }
  }

  // ---- write x = O (coalesced: lanes 0..31 -> consecutive v) ----
#pragma unroll
  for (int fq = 0; fq < 2; ++fq)
#pragma unroll
    for (int fv = 0; fv < 2; ++fv)
#pragma unroll
      for (int r = 0; r < 16; ++r) {
        int row = fq * 32 + (r & 3) + 8 * (r >> 2) + 4 * hi;
        int col = w * 64 + fv * 32 + l31;
        outg[(size_t)(q0 + row) * DVV + col] = oacc[fq][fv][r];
      }
}

extern "C" void kernel_launch(void* const* d_in, const int* in_sizes, int n_in,
                              void* d_out, int out_size, void* d_ws, size_t ws_size,
                              hipStream_t stream) {
  (void)in_sizes; (void)n_in; (void)out_size; (void)ws_size;
  const float* Q = (const float*)d_in[0];
  const float* K = (const float*)d_in[1];
  const float* V = (const float*)d_in[2];
  float* out = (float*)d_out;
  _Float16* Kh = (_Float16*)d_ws;                                   // 8 MB
  _Float16* Vt = (_Float16*)((char*)d_ws + (size_t)NK * DD * 2);    // 8 MB

  convert_k<<<(NK * DD) / (256 * 8), 256, 0, stream>>>(K, Kh);
  transpose_v<<<dim3(NK / 64, DVV / 64), 256, 0, stream>>>(V, Vt);
  attn_main<<<NQ / BM, 256, 0, stream>>>(Q, Kh, Vt, out);
}